// Round 1
// baseline (906.785 us; speedup 1.0000x reference)
//
#include <hip/hip_runtime.h>
#include <hip/hip_bf16.h>

typedef __bf16 v8bf __attribute__((ext_vector_type(8)));
typedef float  v4f  __attribute__((ext_vector_type(4)));
typedef unsigned short u16;
typedef unsigned int   u32;

#define GAS __attribute__((address_space(1)))
#define LAS __attribute__((address_space(3)))

// constants for this problem
constexpr int C_ = 512;
constexpr int S_ = 3136;        // 56*56
constexpr int B_ = 32;
constexpr int M_ = B_ * S_;     // 100352
constexpr float INV_M = 1.0f / (float)M_;

__device__ __forceinline__ void async16(const u16* g, u16* l) {
  __builtin_amdgcn_global_load_lds((const GAS u32*)g, (LAS u32*)l, 16, 0, 0);
}

__device__ __forceinline__ u16 f2bf(float f) {   // RTNE fp32 -> bf16
  u32 u = __builtin_bit_cast(u32, f);
  u += 0x7fffu + ((u >> 16) & 1u);
  return (u16)(u >> 16);
}

// ---------------------------------------------------------------------------
// K1: read X (B,C,S) fp32; write xbf (C, M) bf16 and xbfT (M, C) bf16;
//     accumulate per-channel sums. 64x64 (c,s) tile per block, one b per z.
// ---------------------------------------------------------------------------
__global__ __launch_bounds__(256) void prep_kernel(const float* __restrict__ X,
        u16* __restrict__ xbf, u16* __restrict__ xbfT, float* __restrict__ chsum) {
  __shared__ u16 Ts[64 * 65];            // odd stride: conflict-light transpose
  const int tid = threadIdx.x;
  const int s0 = blockIdx.x * 64;
  const int c0 = blockIdx.y * 64;
  const int b  = blockIdx.z;

  // phase 1: coalesced read, write xbf, stage LDS tile, channel partial sums
  const int i  = tid >> 2;               // channel row 0..63
  const int jc = (tid & 3) * 16;         // s offset
  const float* xp = X + (b * C_ + c0 + i) * S_ + s0 + jc;
  u16* op = xbf + (c0 + i) * M_ + b * S_ + s0 + jc;
  float ssum = 0.f;
  #pragma unroll
  for (int u = 0; u < 4; ++u) {
    float4 xv = *(const float4*)(xp + u * 4);
    ssum += xv.x + xv.y + xv.z + xv.w;
    u16 e0 = f2bf(xv.x), e1 = f2bf(xv.y), e2 = f2bf(xv.z), e3 = f2bf(xv.w);
    *(ushort4*)(op + u * 4) = make_ushort4(e0, e1, e2, e3);
    const int lb = i * 65 + jc + u * 4;
    Ts[lb + 0] = e0; Ts[lb + 1] = e1; Ts[lb + 2] = e2; Ts[lb + 3] = e3;
  }
  ssum += __shfl_down(ssum, 2, 4);
  ssum += __shfl_down(ssum, 1, 4);
  if ((tid & 3) == 0) atomicAdd(&chsum[c0 + i], ssum);
  __syncthreads();

  // phase 2: transposed write; each 8-lane group writes one 128B row segment
  const int lane = tid & 63, wv = tid >> 6;
  #pragma unroll
  for (int p = 0; p < 2; ++p) {
    const int j  = p * 32 + wv * 8 + (lane >> 3);   // s-row 0..63
    const int cc = (lane & 7) * 8;                  // c offset 0..56
    u16 tmp[8];
    #pragma unroll
    for (int e = 0; e < 8; ++e) tmp[e] = Ts[(cc + e) * 65 + j];
    u16* tp = xbfT + (b * S_ + s0 + j) * C_ + c0 + cc;
    *(ushort4*)(tp + 0) = make_ushort4(tmp[0], tmp[1], tmp[2], tmp[3]);
    *(ushort4*)(tp + 4) = make_ushort4(tmp[4], tmp[5], tmp[6], tmp[7]);
  }
}

// ---------------------------------------------------------------------------
// K3: Sigma partials. NT GEMM: part[z][i][j] = sum_{k in slice z} x[i,k]x[j,k]
// 128x128 tile, BK=64, 32-way K split (one b per slice, 49 iters).
// ---------------------------------------------------------------------------
__global__ __launch_bounds__(256, 2) void sigma_gemm(const u16* __restrict__ xbf,
                                                     float* __restrict__ part) {
  __shared__ u16 As[128 * 64];
  __shared__ u16 Bs[128 * 64];
  const int tid = threadIdx.x;
  const int tj = blockIdx.x, ti = blockIdx.y, z = blockIdx.z;
  const int kbase = z * S_;
  const int srow = tid >> 3;
  const int scol = (tid & 7) * 8;
  const int lane = tid & 63, wv = tid >> 6;
  const int wm = (wv & 1) * 64, wn = (wv >> 1) * 64;
  const int lr = lane & 15, lq = lane >> 4;
  const u16* gA = xbf + (ti * 128) * M_ + kbase + scol;
  const u16* gB = xbf + (tj * 128) * M_ + kbase + scol;
  v4f acc[4][4] = {};
  for (int it = 0; it < 49; ++it) {
    const int k0 = it * 64;
    #pragma unroll
    for (int q = 0; q < 4; ++q) {
      const int r = q * 32 + srow;
      async16(gA + r * M_ + k0, &As[r * 64 + scol]);
      async16(gB + r * M_ + k0, &Bs[r * 64 + scol]);
    }
    __syncthreads();
    #pragma unroll
    for (int kk = 0; kk < 2; ++kk) {
      v8bf a[4], b[4];
      #pragma unroll
      for (int x = 0; x < 4; ++x) a[x] = *(const v8bf*)&As[(wm + x*16 + lr)*64 + kk*32 + lq*8];
      #pragma unroll
      for (int x = 0; x < 4; ++x) b[x] = *(const v8bf*)&Bs[(wn + x*16 + lr)*64 + kk*32 + lq*8];
      #pragma unroll
      for (int mi = 0; mi < 4; ++mi)
        #pragma unroll
        for (int ni = 0; ni < 4; ++ni)
          acc[mi][ni] = __builtin_amdgcn_mfma_f32_16x16x32_bf16(a[mi], b[ni], acc[mi][ni], 0, 0, 0);
    }
    __syncthreads();
  }
  float* op = part + z * (C_ * C_);
  #pragma unroll
  for (int mi = 0; mi < 4; ++mi) {
    const int gi = ti * 128 + wm + mi * 16 + lq * 4;
    #pragma unroll
    for (int ni = 0; ni < 4; ++ni) {
      const int gj = tj * 128 + wn + ni * 16 + lr;
      #pragma unroll
      for (int r = 0; r < 4; ++r)
        op[(gi + r) * C_ + gj] = acc[mi][ni][r];
    }
  }
}

// ---------------------------------------------------------------------------
// K4: Sigma = sum_z part/m - mu mu^T + EPS I; accumulate trace atomically.
// ---------------------------------------------------------------------------
__global__ __launch_bounds__(256) void reduce_sigma(const float* __restrict__ part,
        const float* __restrict__ chsum, float* __restrict__ Sigma,
        float* __restrict__ trace) {
  const int idx = blockIdx.x * 256 + threadIdx.x;
  const int i = idx >> 9, j = idx & 511;
  float s = 0.f;
  #pragma unroll 8
  for (int z = 0; z < 32; ++z) s += part[z * (C_ * C_) + idx];
  float val = s * INV_M - (chsum[i] * INV_M) * (chsum[j] * INV_M);
  if (i == j) val += 1e-5f;
  Sigma[idx] = val;
  if (i == j) atomicAdd(trace, val);
}

// ---------------------------------------------------------------------------
// K5: Sigma_N = Sigma/trace; P = I
// ---------------------------------------------------------------------------
__global__ __launch_bounds__(256) void init_ns(const float* __restrict__ Sigma,
        const float* __restrict__ trace, float* __restrict__ SN, float* __restrict__ P) {
  const int idx = blockIdx.x * 256 + threadIdx.x;
  const float rtr = 1.0f / trace[0];
  SN[idx] = Sigma[idx] * rtr;
  P[idx] = ((idx >> 9) == (idx & 511)) ? 1.0f : 0.f;
}

// ---------------------------------------------------------------------------
// K6: fp32 512^3 matmul, 32x32 tile, BK=32.
// mode 0: C[z] = A @ B[z]  (z in {0,1}: T1=P@P, T2=P@SN)
// mode 1: P = 1.5 P - 0.5 A@B
// mode 2: M2 = (A@B)*sqrt(1/trace), also bf16 copy
// Guard: if iter >= *Tptr, no-op (matches reference loop count).
// ---------------------------------------------------------------------------
__global__ __launch_bounds__(256) void mm512_kernel(
    const float* __restrict__ A, const float* __restrict__ Bz0, float* __restrict__ Cz0,
    const float* __restrict__ Bz1, float* __restrict__ Cz1,
    float* __restrict__ P, const float* __restrict__ trace, u16* __restrict__ Cbf,
    const int* __restrict__ Tptr, int iter, int mode) {
  if (Tptr && iter >= Tptr[0]) return;
  const float* Bp = (blockIdx.z == 0) ? Bz0 : Bz1;
  float*       Cp = (blockIdx.z == 0) ? Cz0 : Cz1;
  __shared__ float As[32 * 36];
  __shared__ float Bs[32 * 36];
  const int tid = threadIdx.x;
  const int ro = tid >> 3;
  const int co = (tid & 7) * 4;
  const int ti = blockIdx.y * 32, tj = blockIdx.x * 32;
  float a0 = 0.f, a1 = 0.f, a2 = 0.f, a3 = 0.f;
  for (int k0 = 0; k0 < 512; k0 += 32) {
    float4 av = *(const float4*)(A  + (ti + ro) * 512 + k0 + co);
    float4 bv = *(const float4*)(Bp + (k0 + ro) * 512 + tj + co);
    *(float4*)&As[ro * 36 + co] = av;
    *(float4*)&Bs[ro * 36 + co] = bv;
    __syncthreads();
    #pragma unroll
    for (int k = 0; k < 32; ++k) {
      const float a = As[ro * 36 + k];
      const float4 b = *(const float4*)&Bs[k * 36 + co];
      a0 = fmaf(a, b.x, a0); a1 = fmaf(a, b.y, a1);
      a2 = fmaf(a, b.z, a2); a3 = fmaf(a, b.w, a3);
    }
    __syncthreads();
  }
  const int oidx = (ti + ro) * 512 + tj + co;
  if (mode == 0) {
    Cp[oidx + 0] = a0; Cp[oidx + 1] = a1; Cp[oidx + 2] = a2; Cp[oidx + 3] = a3;
  } else if (mode == 1) {
    float4 pv = *(const float4*)(P + oidx);
    pv.x = 1.5f * pv.x - 0.5f * a0;
    pv.y = 1.5f * pv.y - 0.5f * a1;
    pv.z = 1.5f * pv.z - 0.5f * a2;
    pv.w = 1.5f * pv.w - 0.5f * a3;
    *(float4*)(P + oidx) = pv;
  } else {
    const float sc = sqrtf(1.0f / trace[0]);
    a0 *= sc; a1 *= sc; a2 *= sc; a3 *= sc;
    Cp[oidx + 0] = a0; Cp[oidx + 1] = a1; Cp[oidx + 2] = a2; Cp[oidx + 3] = a3;
    *(ushort4*)(Cbf + oidx) = make_ushort4(f2bf(a0), f2bf(a1), f2bf(a2), f2bf(a3));
  }
}

// ---------------------------------------------------------------------------
// K8: v[d] = sum_c M2[d,c] * mean[c]
// ---------------------------------------------------------------------------
__global__ __launch_bounds__(256) void calc_v(const float* __restrict__ M2f,
        const float* __restrict__ chsum, float* __restrict__ v) {
  const int d = blockIdx.x * 256 + threadIdx.x;
  float s = 0.f;
  for (int c = 0; c < 512; ++c) s += M2f[d * 512 + c] * (chsum[c] * INV_M);
  v[d] = s;
}

// ---------------------------------------------------------------------------
// K9: out[b,d,s] = sum_c M2bf[d,c] * xbfT[b*S+s, c] - v[d]
// NT GEMM: M=512 (d, 4 tiles), N=100352 (m, 784 tiles), K=512 (8 BK iters)
// ---------------------------------------------------------------------------
__global__ __launch_bounds__(256, 2) void out_gemm(const u16* __restrict__ Abf,
        const u16* __restrict__ Bt, const float* __restrict__ v, float* __restrict__ out) {
  __shared__ u16 As[128 * 64];
  __shared__ u16 Bs[128 * 64];
  const int tid = threadIdx.x;
  const int tn = blockIdx.x, td = blockIdx.y;
  const int srow = tid >> 3, scol = (tid & 7) * 8;
  const int lane = tid & 63, wv = tid >> 6;
  const int wm = (wv & 1) * 64, wn = (wv >> 1) * 64;
  const int lr = lane & 15, lq = lane >> 4;
  const u16* gA = Abf + (td * 128) * 512 + scol;
  const u16* gB = Bt + (tn * 128) * 512 + scol;
  v4f acc[4][4] = {};
  for (int it = 0; it < 8; ++it) {
    const int k0 = it * 64;
    #pragma unroll
    for (int q = 0; q < 4; ++q) {
      const int r = q * 32 + srow;
      async16(gA + r * 512 + k0, &As[r * 64 + scol]);
      async16(gB + r * 512 + k0, &Bs[r * 64 + scol]);
    }
    __syncthreads();
    #pragma unroll
    for (int kk = 0; kk < 2; ++kk) {
      v8bf a[4], b[4];
      #pragma unroll
      for (int x = 0; x < 4; ++x) a[x] = *(const v8bf*)&As[(wm + x*16 + lr)*64 + kk*32 + lq*8];
      #pragma unroll
      for (int x = 0; x < 4; ++x) b[x] = *(const v8bf*)&Bs[(wn + x*16 + lr)*64 + kk*32 + lq*8];
      #pragma unroll
      for (int mi = 0; mi < 4; ++mi)
        #pragma unroll
        for (int ni = 0; ni < 4; ++ni)
          acc[mi][ni] = __builtin_amdgcn_mfma_f32_16x16x32_bf16(a[mi], b[ni], acc[mi][ni], 0, 0, 0);
    }
    __syncthreads();
  }
  #pragma unroll
  for (int mi = 0; mi < 4; ++mi) {
    const int d0 = td * 128 + wm + mi * 16 + lq * 4;
    const float vd0 = v[d0 + 0], vd1 = v[d0 + 1], vd2 = v[d0 + 2], vd3 = v[d0 + 3];
    #pragma unroll
    for (int ni = 0; ni < 4; ++ni) {
      const unsigned mcol = tn * 128 + wn + ni * 16 + lr;
      const unsigned bb = mcol / 3136u;          // magic-mul div (const)
      const unsigned ss = mcol - bb * 3136u;
      const int obase = (int)(bb * 512u) * 3136 + (int)ss;
      out[obase + (d0 + 0) * 3136] = acc[mi][ni][0] - vd0;
      out[obase + (d0 + 1) * 3136] = acc[mi][ni][1] - vd1;
      out[obase + (d0 + 2) * 3136] = acc[mi][ni][2] - vd2;
      out[obase + (d0 + 3) * 3136] = acc[mi][ni][3] - vd3;
    }
  }
}

// ---------------------------------------------------------------------------
extern "C" void kernel_launch(void* const* d_in, const int* in_sizes, int n_in,
                              void* d_out, int out_size, void* d_ws, size_t ws_size,
                              hipStream_t stream) {
  const float* X   = (const float*)d_in[0];
  const float* rot = (const float*)d_in[1];
  const int*   T   = (const int*)d_in[2];
  float* out = (float*)d_out;

  char* ws = (char*)d_ws;
  size_t off = 0;
  auto alloc = [&](size_t bytes) -> char* {
    char* p = ws + off;
    off += (bytes + 255) & ~(size_t)255;
    return p;
  };
  u16*   xbf   = (u16*)alloc((size_t)C_ * M_ * 2);     // 102.8 MB
  u16*   xbfT  = (u16*)alloc((size_t)M_ * C_ * 2);     // 102.8 MB
  float* part  = (float*)alloc((size_t)32 * C_ * C_ * 4);
  float* Sigma = (float*)alloc((size_t)C_ * C_ * 4);
  float* SN    = (float*)alloc((size_t)C_ * C_ * 4);
  float* P     = (float*)alloc((size_t)C_ * C_ * 4);
  float* T1    = (float*)alloc((size_t)C_ * C_ * 4);
  float* T2    = (float*)alloc((size_t)C_ * C_ * 4);
  float* M2f   = (float*)alloc((size_t)C_ * C_ * 4);
  u16*   M2bf  = (u16*)alloc((size_t)C_ * C_ * 2);
  float* chsum = (float*)alloc(2048);
  float* trace = (float*)alloc(256);
  float* v     = (float*)alloc(2048);
  (void)ws_size; (void)in_sizes; (void)n_in; (void)out_size;

  // zero the atomic accumulators (chsum + trace are contiguous)
  hipMemsetAsync(chsum, 0, 2048 + 256, stream);

  prep_kernel<<<dim3(49, 8, 32), 256, 0, stream>>>(X, xbf, xbfT, chsum);
  sigma_gemm<<<dim3(4, 4, 32), 256, 0, stream>>>(xbf, part);
  reduce_sigma<<<dim3(1024), 256, 0, stream>>>(part, chsum, Sigma, trace);
  init_ns<<<dim3(1024), 256, 0, stream>>>(Sigma, trace, SN, P);

  for (int iter = 0; iter < 10; ++iter) {
    // z=0: T1 = P@P ; z=1: T2 = P@SN
    mm512_kernel<<<dim3(16, 16, 2), 256, 0, stream>>>(P, P, T1, SN, T2, P, trace, M2bf, T, iter, 0);
    // P = 1.5P - 0.5 * T1@T2  (= 1.5P - 0.5 P^3 SN by associativity)
    mm512_kernel<<<dim3(16, 16, 1), 256, 0, stream>>>(T1, T2, T1, T2, T1, P, trace, M2bf, T, iter, 1);
  }
  // M2 = rot @ P * sqrt(1/trace)  (fp32 + bf16 copies)
  mm512_kernel<<<dim3(16, 16, 1), 256, 0, stream>>>(rot, P, M2f, P, M2f, P, trace, M2bf, nullptr, 0, 2);
  calc_v<<<dim3(2), 256, 0, stream>>>(M2f, chsum, v);
  out_gemm<<<dim3(784, 4), 256, 0, stream>>>(M2bf, xbfT, v, out);
}